// Round 1
// baseline (560.877 us; speedup 1.0000x reference)
//
#include <hip/hip_runtime.h>
#include <utility>
#include <cstddef>

// ---------------- compile-time Ivanic-Ruedenberg tables ----------------

struct Term { int o; int r; int a; float c; };
struct LTable { int n; Term t[1024]; };

constexpr double csqrt(double x) {
    if (x <= 0.0) return 0.0;
    double g = x < 1.0 ? 1.0 : x;
    for (int i = 0; i < 50; ++i) g = 0.5 * (g + x / g);
    return g;
}
constexpr int cabs_i(int x) { return x < 0 ? -x : x; }
constexpr int cmax_i(int a, int b) { return a > b ? a : b; }

constexpr void add_p(LTable& T, int o, double scale, int i, int a, int b, int l) {
    int lp = l - 1;
    int np = 2 * lp + 1;
    int row = i + 1;
    if (b == l) {
        T.t[T.n++] = Term{o, row * 3 + 2, (a + lp) * np + 2 * lp, (float)scale};
        T.t[T.n++] = Term{o, row * 3 + 0, (a + lp) * np + 0,      (float)(-scale)};
    } else if (b == -l) {
        T.t[T.n++] = Term{o, row * 3 + 2, (a + lp) * np + 0,      (float)scale};
        T.t[T.n++] = Term{o, row * 3 + 0, (a + lp) * np + 2 * lp, (float)scale};
    } else {
        T.t[T.n++] = Term{o, row * 3 + 1, (a + lp) * np + (b + lp), (float)scale};
    }
}

constexpr LTable ru_table(int l) {
    LTable T{};
    int n = 2 * l + 1;
    for (int m = -l; m <= l; ++m) {
        for (int mp = -l; mp <= l; ++mp) {
            double denom = (cabs_i(mp) == l) ? (double)((2 * l) * (2 * l - 1))
                                             : (double)((l + mp) * (l - mp));
            double d0 = (m == 0) ? 1.0 : 0.0;
            double u = csqrt((double)((l + m) * (l - m)) / denom);
            double v = 0.5 * csqrt((1.0 + d0) * (l + cabs_i(m) - 1) * (l + cabs_i(m)) / denom)
                       * (1.0 - 2.0 * d0);
            double w = -0.5 * csqrt((double)cmax_i(l - cabs_i(m) - 1, 0) * (l - cabs_i(m)) / denom)
                       * (1.0 - d0);
            int o = (m + l) * n + (mp + l);
            if (u != 0.0) add_p(T, o, u, 0, m, mp, l);
            if (v != 0.0) {
                if (m == 0) {
                    add_p(T, o, v, 1, 1, mp, l);
                    add_p(T, o, v, -1, -1, mp, l);
                } else if (m > 0) {
                    double s = (m == 1) ? csqrt(2.0) : 1.0;
                    add_p(T, o, v * s, 1, m - 1, mp, l);
                    if (m != 1) add_p(T, o, -v, -1, -m + 1, mp, l);
                } else {
                    if (m != -1) add_p(T, o, v, 1, m + 1, mp, l);
                    double s = (m == -1) ? csqrt(2.0) : 1.0;
                    add_p(T, o, v * s, -1, -m - 1, mp, l);
                }
            }
            if (w != 0.0) {
                if (m > 0) {
                    add_p(T, o, w, 1, m + 1, mp, l);
                    add_p(T, o, w, -1, -m - 1, mp, l);
                } else {
                    add_p(T, o, w, 1, m - 1, mp, l);
                    add_p(T, o, -w, -1, -m + 1, mp, l);
                }
            }
        }
    }
    return T;
}

inline constexpr LTable T2 = ru_table(2);
inline constexpr LTable T3 = ru_table(3);
inline constexpr LTable T4 = ru_table(4);

// terms for a given output entry are contiguous by construction (m-major, mp-minor)
template<const LTable& T>
constexpr int er_start(int e) {
    for (int i = 0; i < T.n; ++i) if (T.t[i].o == e) return i;
    return 0;
}
template<const LTable& T>
constexpr int er_cnt(int e) {
    int c = 0;
    for (int i = 0; i < T.n; ++i) if (T.t[i].o == e) ++c;
    return c;
}

// image offset of flat index a of D^{l-1} inside the 25x25 block-diagonal row
constexpr int poff(int a, int l) {
    int lp = l - 1;
    int n = 2 * lp + 1;
    int rr = a / n, cc = a % n;
    return (lp * lp + rr) * 25 + (lp * lp + cc);
}

// one term's product: R1[r] (regs) * P[idx]. For l==2 (PREG) P is the reg R1
// array indexed by flat a; for l>=3, P is the LDS row indexed via poff().
template<const LTable& T, int S, bool PREG, int l, int K>
__device__ __forceinline__ float term_val(const float* R1, const float* P) {
    constexpr Term tm = T.t[S + K];
    constexpr int idx = PREG ? tm.a : poff(tm.a, l);
    return R1[tm.r] * P[idx];
}

template<const LTable& T, int S, bool PREG, int l, size_t... K>
__device__ __forceinline__ float sum_terms(const float* R1, const float* P,
                                           std::index_sequence<K...>) {
    float a = 0.0f;
    ((a = fmaf(T.t[S + (int)K].c, term_val<T, S, PREG, l, (int)K>(R1, P), a)), ...);
    return a;
}

// compute one entry of block l and ds_write it at its compile-time image slot
template<const LTable& T, int l, bool PREG, int e>
__device__ __forceinline__ void entry_one(const float* R1, const float* P,
                                          float* row) {
    constexpr int S = er_start<T>(e);
    constexpr int C = er_cnt<T>(e);
    float v = sum_terms<T, S, PREG, l>(R1, P, std::make_index_sequence<C>{});
    constexpr int d = 2 * l + 1;
    constexpr int off = (l * l + e / d) * 25 + (l * l + e % d);
    row[off] = v;
}

// interleaved entry assignment: group G computes entries {G, G+8, G+16, ...}
// (spreads heavy edge columns across groups for balance)
template<const LTable& T, int l, bool PREG, int G, size_t... K>
__device__ __forceinline__ void group_entries(const float* R1, const float* P,
                                              float* row, std::index_sequence<K...>) {
    (entry_one<T, l, PREG, G + 8 * (int)K>(R1, P, row), ...);
}

template<const LTable& T, int l, bool PREG>
__device__ __forceinline__ void group_dispatch(int g, const float* R1,
                                               const float* P, float* row) {
    constexpr int NE = (2 * l + 1) * (2 * l + 1);
    if      (g == 0) group_entries<T, l, PREG, 0>(R1, P, row, std::make_index_sequence<(NE - 0 + 7) / 8>{});
    else if (g == 1) group_entries<T, l, PREG, 1>(R1, P, row, std::make_index_sequence<(NE - 1 + 7) / 8>{});
    else if (g == 2) group_entries<T, l, PREG, 2>(R1, P, row, std::make_index_sequence<(NE - 2 + 7) / 8>{});
    else if (g == 3) group_entries<T, l, PREG, 3>(R1, P, row, std::make_index_sequence<(NE - 3 + 7) / 8>{});
    else if (g == 4) group_entries<T, l, PREG, 4>(R1, P, row, std::make_index_sequence<(NE - 4 + 7) / 8>{});
    else if (g == 5) group_entries<T, l, PREG, 5>(R1, P, row, std::make_index_sequence<(NE - 5 + 7) / 8>{});
    else if (g == 6) group_entries<T, l, PREG, 6>(R1, P, row, std::make_index_sequence<(NE - 6 + 7) / 8>{});
    else             group_entries<T, l, PREG, 7>(R1, P, row, std::make_index_sequence<(NE - 7 + 7) / 8>{});
}

template<size_t... E>
__device__ __forceinline__ void write_l1(const float* D1, float* row,
                                         std::index_sequence<E...>) {
    ((row[(1 + (int)E / 3) * 25 + (1 + (int)E % 3)] = D1[E]), ...);
}

// native clang vector type: required by __builtin_nontemporal_store
typedef float v4f __attribute__((ext_vector_type(4)));

// ---------------- fused kernel ----------------
// Block: 256 threads, 256 points, 8 chunks of 32 points.
// LDS image 32x625 floats (80,000 B) -> 2 blocks/CU (cross-block overlap of
// compute phases with the HBM-streaming copy phases).
//
// ENTRY-PARALLEL compute (the change vs the previous version): thread t
// serves point p = t&31 of the chunk with entry-group g = t>>5. Every
// thread rebuilds its point's R1 from xyz (L1-hit loads, ~30 VALU), then:
//   phase A: l0+l1 (g==0) and D2 entries (split 8 ways, P = R1 in regs)
//   phase B: D3 entries (split 8 ways, P = D2 ds_read from the image)
//   phase C: D4 entries (split 8 ways, P = D3 ds_read from the image)
//   phase D: coalesced nontemporal v4f copy image -> global
// All 256 lanes now compute every phase (previously 32 of 256), register
// pressure collapses to R1[9]+temps, and LDS accesses stay conflict-free:
// addr/4 = 625*p + const  ->  bank = (17p + const) % 32, a permutation in p
// per half-wave; the two wave halves give only free 2-way aliasing.

__global__ __launch_bounds__(256, 2)
void wigner_fused_kernel(const float* __restrict__ xyz, float* __restrict__ out, int Ntot) {
    __shared__ float img[32 * 625];

    const int t = threadIdx.x;
    const int p = t & 31;
    const int g = t >> 5;

    // zero whole image once (structural-zero slots are never rewritten)
    v4f* b4 = (v4f*)img;
    const v4f z4 = {0.0f, 0.0f, 0.0f, 0.0f};
#pragma unroll 4
    for (int k = t; k < 5000; k += 256) b4[k] = z4;
    __syncthreads();

    const long long blk_f = (long long)blockIdx.x * 256 * 625;
    float* row = img + p * 625;

    for (int c = 0; c < 8; ++c) {
        const int base_pt = blockIdx.x * 256 + c * 32;
        if (base_pt >= Ntot) break;  // uniform across block
        const int vp = min(32, Ntot - base_pt);
        const int pt = base_pt + p;
        const bool live = (p < vp);

        // every thread rebuilds its point's trig + R1 (redundant x8, cheap)
        float x = 0.0f, y = 0.0f, z = 1.0f;
        if (live) {
            x = xyz[3 * pt + 0];
            y = xyz[3 * pt + 1];
            z = xyz[3 * pt + 2];
        }
        const float r2 = x * x + y * y + z * z;
        const float rinv = rsqrtf(fmaxf(r2, 1e-24f));
        const float ct = fminf(fmaxf(z * rinv, -1.0f), 1.0f);
        const float st = sqrtf(fmaxf(1.0f - ct * ct, 0.0f));
        const float rxy2 = x * x + y * y;
        float cp = 1.0f, sp = 0.0f;
        if (rxy2 > 0.0f) {
            const float ri = rsqrtf(rxy2);
            cp = x * ri;
            sp = y * ri;
        }

        // R1 in real-SH l=1 basis order (y,z,x), row-major 3x3
        const float R1[9] = {cp,      0.0f, -sp,
                             st * sp, ct,   st * cp,
                             ct * sp, -st,  ct * cp};

        // phase A: l0, l1, D2 (P = R1 in registers)
        if (live) {
            if (g == 0) {
                row[0] = 1.0f;
                write_l1(R1, row, std::make_index_sequence<9>{});
            }
            group_dispatch<T2, 2, true>(g, R1, R1, row);
        }
        __syncthreads();

        // phase B: D3 (P = D2 slots of the image)
        if (live) group_dispatch<T3, 3, false>(g, R1, row, row);
        __syncthreads();

        // phase C: D4 (P = D3 slots of the image)
        if (live) group_dispatch<T4, 4, false>(g, R1, row, row);
        __syncthreads();

        // phase D: copy image -> global, contiguous 16B nontemporal stream
        const long long out_f = blk_f + (long long)c * 32 * 625;
        if (vp == 32) {
            const v4f* src = (const v4f*)img;
            v4f* dst = (v4f*)(out + out_f);
#pragma unroll 4
            for (int k = t; k < 5000; k += 256) {
                __builtin_nontemporal_store(src[k], dst + k);
            }
        } else {
            const int vf = vp * 625;
            for (int k = t; k < vf; k += 256) {
                out[out_f + k] = img[k];
            }
        }
        __syncthreads();
    }
}

extern "C" void kernel_launch(void* const* d_in, const int* in_sizes, int n_in,
                              void* d_out, int out_size, void* d_ws, size_t ws_size,
                              hipStream_t stream) {
    const float* xyz = (const float*)d_in[0];
    float* out = (float*)d_out;
    const int N = in_sizes[0] / 3;
    const int blocks = (N + 255) / 256;
    hipLaunchKernelGGL(wigner_fused_kernel, dim3(blocks), dim3(256), 0, stream,
                       xyz, out, N);
}